// Round 12
// baseline (136.592 us; speedup 1.0000x reference)
//
#include <hip/hip_runtime.h>
#include <hip/hip_bf16.h>
#include <math.h>

#define BB 16
#define NN_ 4096
#define DD 512
#define LL 64
#define SCALE 0.044194173824159216f
#define RMS_EPS 1e-6f
#define MASKVAL -3.0e38f
#define PSZ (BB * LL * DD)   // 524288
#define ZCH 32               // N-chunks (128 tokens each, 2 tiles of 64)

using bf16x8 = __attribute__((ext_vector_type(8))) short;
using f32x4  = __attribute__((ext_vector_type(4))) float;

__device__ __forceinline__ unsigned short f2bf(float x) {
    return __bfloat16_as_ushort(__float2bfloat16(x));
}

// ---------------- K1: qproj = query @ Wq + bq ----------------
__global__ __launch_bounds__(256) void k_qproj(const float* __restrict__ query, const float* __restrict__ Wq,
                                               const float* __restrict__ bq, float* __restrict__ qproj) {
    const int b = blockIdx.y;
    const int dl = threadIdx.x & 63;
    const int d = (blockIdx.x << 6) + dl;
    const int wv = threadIdx.x >> 6;
    __shared__ float q[DD];
    __shared__ float red[4][64];
    for (int e = threadIdx.x; e < DD; e += 256) q[e] = query[b * DD + e];
    __syncthreads();
    float acc = 0.f;
    #pragma unroll 8
    for (int i = 0; i < 128; ++i) {
        const int e = (wv << 7) + i;
        acc += q[e] * Wq[(size_t)e * DD + d];
    }
    red[wv][dl] = acc;
    __syncthreads();
    if (threadIdx.x < 64) {
        const int dd = (blockIdx.x << 6) + threadIdx.x;
        qproj[(size_t)b * DD + dd] = red[0][threadIdx.x] + red[1][threadIdx.x] +
                                     red[2][threadIdx.x] + red[3][threadIdx.x] + bq[dd];
    }
}

// ---------------- K2: Lk/Qk = rows @ Wk^T, sbL/sbQ = rows . bk ----------------
__global__ __launch_bounds__(256) void k_lkqk(const float* __restrict__ latents, const float* __restrict__ qproj,
                                              const float* __restrict__ Wk, const float* __restrict__ bk,
                                              float* __restrict__ Lk, float* __restrict__ Qk,
                                              float* __restrict__ sbL, float* __restrict__ sbQ) {
    const int r = blockIdx.y;
    const int e0 = blockIdx.x << 6;
    const int tid = threadIdx.x;
    __shared__ float row[DD];
    const float* src = (r < LL) ? (latents + (size_t)r * DD) : (qproj + (size_t)(r - LL) * DD);
    for (int dd = tid; dd < DD; dd += 256) row[dd] = src[dd];
    __syncthreads();
    const int e = e0 + (tid >> 2);
    const int part = tid & 3;
    const float4* w4 = (const float4*)(Wk + (size_t)e * DD);
    const float4* r4 = (const float4*)row;
    float acc = 0.f;
    #pragma unroll 8
    for (int j = 0; j < 32; ++j) {
        const int d4 = part + (j << 2);
        const float4 w = w4[d4], rr = r4[d4];
        acc += w.x * rr.x + w.y * rr.y + w.z * rr.z + w.w * rr.w;
    }
    acc += __shfl_xor(acc, 1);
    acc += __shfl_xor(acc, 2);
    if (part == 0) {
        if (r < LL) Lk[(size_t)r * DD + e] = acc;
        else        Qk[(size_t)(r - LL) * DD + e] = acc;
    }
    if (blockIdx.x == 0 && tid < 64) {
        float p = 0.f;
        #pragma unroll
        for (int dd = tid; dd < DD; dd += 64) p += bk[dd] * row[dd];
        #pragma unroll
        for (int off = 32; off > 0; off >>= 1) p += __shfl_xor(p, off);
        if (tid == 0) { if (r < LL) sbL[r] = p; else sbQ[r - LL] = p; }
    }
}

// ---------------- K2b: LQbf[b][l][d] = bf16(Lk[l][d] + Qk[b][d]) ----------------
__global__ __launch_bounds__(256) void k_lqbf(const float* __restrict__ Lk, const float* __restrict__ Qk,
                                              unsigned short* __restrict__ LQbf) {
    const int l = blockIdx.x, b = blockIdx.y;
    const int d = threadIdx.x << 1;
    const float2 lv = *(const float2*)&Lk[(size_t)l * DD + d];
    const float2 qv = *(const float2*)&Qk[(size_t)b * DD + d];
    const unsigned o = (unsigned)f2bf(lv.x + qv.x) | ((unsigned)f2bf(lv.y + qv.y) << 16);
    *(unsigned*)&LQbf[(size_t)((b << 6) + l) * DD + d] = o;
}

// ---------------- K3: fused flash (v9: raw-barrier counted-wait phase1, e-split) ----------------
// grid (64, 16): x = (eh<<5)|z; eh pair x/x+32 shares token chunk (same XCD). 512 thr, 2 blocks/CU.
__global__ __launch_bounds__(512, 2) void k_flash(const float* __restrict__ tokens,
                                                  const unsigned short* __restrict__ LQbf,
                                                  const float* __restrict__ sbL, const float* __restrict__ sbQ,
                                                  const int* __restrict__ pmask,
                                                  _Float16* __restrict__ part,
                                                  float* __restrict__ mz, float* __restrict__ sz) {
    const int z = blockIdx.x & 31;
    const int eh = blockIdx.x >> 5;
    const int b = blockIdx.y;
    const int tid = threadIdx.x;
    const int lane = tid & 63, w = tid >> 6;
    const int r16 = lane & 15, kl = lane >> 4;

    __shared__ int sB[2][64][36];         // QK^T token slice [n][d-word], dbuf
    __shared__ unsigned short sP[64][72]; // P bf16 [l][n(64)]
    __shared__ int sTw[8][32][20];        // per-wave PV window [e(32)][pair+pad], XOR swizzled
    __shared__ float s_mn[64], s_sum[64], s_rr[64];
    __shared__ float s_pmax[2][64], s_psum[2][64];

    const int lq = (w & 3) << 4;        // QK^T wave l-block (16)
    const int nq = (w >> 2) << 5;       // QK^T wave n-block (32)

    f32x4 acc[4][2];                    // PV: 64 l x 32 e per wave
    #pragma unroll
    for (int m = 0; m < 4; ++m)
        #pragma unroll
        for (int ef = 0; ef < 2; ++ef)
            acc[m][ef] = (f32x4){0.f, 0.f, 0.f, 0.f};

    if (tid < 64) { s_mn[tid] = MASKVAL; s_sum[tid] = 0.f; }

    const float sq = sbQ[b];
    const unsigned short* lqrow = &LQbf[(size_t)((b << 6) + lq + r16) * DD];
    float sbl[4];
    #pragma unroll
    for (int q = 0; q < 4; ++q) sbl[q] = sbL[lq + (kl << 2) + q];

    const int p1_pair = tid >> 4;         // token pair 0..31
    const int p1_d4 = (tid & 15) << 2;    // d offset
    const int e0w = (eh << 8) + (w << 5); // PV wave e-slice base (32)
    __syncthreads();

    for (int t = 0; t < 2; ++t) {
        const int n0 = (z << 7) + (t << 6);
        f32x4 accS[2];
        accS[0] = (f32x4){0.f, 0.f, 0.f, 0.f};
        accS[1] = (f32x4){0.f, 0.f, 0.f, 0.f};

        // ---- phase 1: QK^T, depth-4 rolling register prefetch + raw barriers ----
        const float* tbase = &tokens[(size_t)((b << 12) + n0 + (p1_pair << 1)) * DD + p1_d4];
        float4 R0[4], R1[4];
        #pragma unroll
        for (int s = 0; s < 4; ++s) {
            R0[s] = *(const float4*)(tbase + (s << 6));
            R1[s] = *(const float4*)(tbase + DD + (s << 6));
        }
        #pragma unroll
        for (int s8 = 0; s8 < 8; ++s8) {
            const int cur = s8 & 1, slot = s8 & 3;
            {
                int2 w0, w1;
                w0.x = (int)((unsigned)f2bf(R0[slot].x) | ((unsigned)f2bf(R0[slot].y) << 16));
                w0.y = (int)((unsigned)f2bf(R0[slot].z) | ((unsigned)f2bf(R0[slot].w) << 16));
                w1.x = (int)((unsigned)f2bf(R1[slot].x) | ((unsigned)f2bf(R1[slot].y) << 16));
                w1.y = (int)((unsigned)f2bf(R1[slot].z) | ((unsigned)f2bf(R1[slot].w) << 16));
                *(int2*)&sB[cur][(p1_pair << 1)][p1_d4 >> 1] = w0;
                *(int2*)&sB[cur][(p1_pair << 1) + 1][p1_d4 >> 1] = w1;
            }
            if (s8 < 4) {   // refill slot for slice s8+4 (stays in flight across raw barriers)
                R0[slot] = *(const float4*)(tbase + ((s8 + 4) << 6));
                R1[slot] = *(const float4*)(tbase + DD + ((s8 + 4) << 6));
            }
            asm volatile("s_waitcnt lgkmcnt(0)" ::: "memory");
            __builtin_amdgcn_sched_barrier(0);
            __builtin_amdgcn_s_barrier();     // raw: no vmem drain, prefetch survives
            #pragma unroll
            for (int kk2 = 0; kk2 < 2; ++kk2) {
                const bf16x8 af = *(const bf16x8*)&lqrow[(s8 << 6) + (kk2 << 5) + (kl << 3)];
                #pragma unroll
                for (int nf = 0; nf < 2; ++nf) {
                    const bf16x8 bfr = *(const bf16x8*)&sB[cur][nq + (nf << 4) + r16][(kk2 << 4) + (kl << 2)];
                    accS[nf] = __builtin_amdgcn_mfma_f32_16x16x32_bf16(af, bfr, accS[nf], 0, 0, 0);
                }
            }
        }
        __syncthreads();   // close phase 1 (no outstanding prefetch now)

        // ---- epilogue: bias+scale+mask, in-register stats ----
        float sv[2][4], tm4[4];
        #pragma unroll
        for (int nf = 0; nf < 2; ++nf) {
            const int ncol = nq + (nf << 4) + r16;
            const int pm = pmask[(size_t)(b << 12) + n0 + ncol];
            #pragma unroll
            for (int q = 0; q < 4; ++q) {
                const float sval = (accS[nf][q] + sbl[q] + sq) * SCALE;
                sv[nf][q] = pm ? MASKVAL : sval;
            }
        }
        #pragma unroll
        for (int q = 0; q < 4; ++q) tm4[q] = fmaxf(sv[0][q], sv[1][q]);
        #pragma unroll
        for (int off = 1; off <= 8; off <<= 1)
            #pragma unroll
            for (int q = 0; q < 4; ++q) tm4[q] = fmaxf(tm4[q], __shfl_xor(tm4[q], off));
        if (r16 == 0) {
            #pragma unroll
            for (int q = 0; q < 4; ++q) s_pmax[w >> 2][lq + (kl << 2) + q] = tm4[q];
        }
        __syncthreads();
        if (tid < 64) {
            const float tmx = fmaxf(s_pmax[0][tid], s_pmax[1][tid]);
            const float mo = s_mn[tid];
            const float mn = fmaxf(mo, tmx);
            s_rr[tid] = __expf(mo - mn);
            s_mn[tid] = mn;
        }
        __syncthreads();
        float ps4[4];
        #pragma unroll
        for (int q = 0; q < 4; ++q) {
            const int l = lq + (kl << 2) + q;
            const float mn = s_mn[l];
            const float p0 = __expf(sv[0][q] - mn);
            const float p1 = __expf(sv[1][q] - mn);
            sP[l][nq + r16] = f2bf(p0);
            sP[l][nq + 16 + r16] = f2bf(p1);
            ps4[q] = p0 + p1;
        }
        #pragma unroll
        for (int off = 1; off <= 8; off <<= 1)
            #pragma unroll
            for (int q = 0; q < 4; ++q) ps4[q] += __shfl_xor(ps4[q], off);
        if (r16 == 0) {
            #pragma unroll
            for (int q = 0; q < 4; ++q) s_psum[w >> 2][lq + (kl << 2) + q] = ps4[q];
        }
        #pragma unroll
        for (int m = 0; m < 4; ++m) {
            #pragma unroll
            for (int q = 0; q < 4; ++q) {
                const float rrr = s_rr[(m << 4) + (kl << 2) + q];
                #pragma unroll
                for (int ef = 0; ef < 2; ++ef) acc[m][ef][q] *= rrr;
            }
        }
        __syncthreads();
        if (tid < 64) s_sum[tid] = s_sum[tid] * s_rr[tid] + s_psum[0][tid] + s_psum[1][tid];

        // ---- phase 2: PV, per-wave 32-e slice, loads issued before converts ----
        #pragma unroll
        for (int kk = 0; kk < 2; ++kk) {
            float4 T0[2], T1[2];
            #pragma unroll
            for (int rep = 0; rep < 2; ++rep) {
                const int p = (lane >> 3) + (rep << 3);       // pair 0..15
                const int e4 = (lane & 7) << 2;               // e offset 0..28
                const float* tp = &tokens[(size_t)((b << 12) + n0 + (kk << 5) + (p << 1)) * DD + e0w + e4];
                T0[rep] = *(const float4*)tp;
                T1[rep] = *(const float4*)(tp + DD);
            }
            #pragma unroll
            for (int rep = 0; rep < 2; ++rep) {
                const int p = (lane >> 3) + (rep << 3);
                const int e4 = (lane & 7) << 2;
                const float* a0 = (const float*)&T0[rep];
                const float* a1 = (const float*)&T1[rep];
                #pragma unroll
                for (int j = 0; j < 4; ++j) {
                    const int e = e4 + j;
                    const int col = p ^ (((((e >> 2) ^ (e >> 4))) & 3) << 2);
                    sTw[w][e][col] = (int)((unsigned)f2bf(a0[j]) | ((unsigned)f2bf(a1[j]) << 16));
                }
            }
            bf16x8 pa[4];
            #pragma unroll
            for (int m = 0; m < 4; ++m)
                pa[m] = *(const bf16x8*)&sP[(m << 4) + r16][(kk << 5) + (kl << 3)];
            #pragma unroll
            for (int ef = 0; ef < 2; ++ef) {
                const int e = (ef << 4) + r16;
                const int col4 = (kl << 2) ^ (((((e >> 2) ^ (e >> 4))) & 3) << 2);
                const bf16x8 bv = *(const bf16x8*)&sTw[w][e][col4];
                #pragma unroll
                for (int m = 0; m < 4; ++m)
                    acc[m][ef] = __builtin_amdgcn_mfma_f32_16x16x32_bf16(pa[m], bv, acc[m][ef], 0, 0, 0);
            }
        }
        __syncthreads();
    }

    // ---- write partials (f16) ----
    #pragma unroll
    for (int m = 0; m < 4; ++m) {
        #pragma unroll
        for (int ef = 0; ef < 2; ++ef) {
            #pragma unroll
            for (int q = 0; q < 4; ++q) {
                const int l = (m << 4) + (kl << 2) + q;
                const int e = e0w + (ef << 4) + r16;
                part[(size_t)((z << 10) + (b << 6) + l) * DD + e] = (_Float16)acc[m][ef][q];
            }
        }
    }
    if (tid < 64) {
        mz[(z << 10) + (b << 6) + tid] = s_mn[tid];
        sz[(z << 10) + (b << 6) + tid] = s_sum[tid];
    }
}

// ---------------- K4: combine chunks with rescale + divide (vectorized loads) ----------------
__global__ __launch_bounds__(256) void k_combine(const _Float16* __restrict__ part,
                                                 const float* __restrict__ mz, const float* __restrict__ sz,
                                                 float* __restrict__ pacc, float* __restrict__ dmg) {
    const int row = blockIdx.x;   // b*64 + l
    const int t = threadIdx.x;
    float mg = MASKVAL;
    float mv[ZCH];
    #pragma unroll
    for (int zz = 0; zz < ZCH; ++zz) {
        mv[zz] = mz[(zz << 10) + row];
        mg = fmaxf(mg, mv[zz]);
    }
    float den = 0.f;
    float fz[ZCH];
    #pragma unroll
    for (int zz = 0; zz < ZCH; ++zz) {
        fz[zz] = __expf(mv[zz] - mg);
        den += sz[(zz << 10) + row] * fz[zz];
    }
    // thread handles e = 2t, 2t+1 via one uint (2 f16) per chunk
    const unsigned* p32 = (const unsigned*)part;
    const unsigned base32 = (unsigned)(row << 8) + t;    // (row*512 + 2t)/2
    float a0 = 0.f, a1 = 0.f;
    #pragma unroll 8
    for (int zz = 0; zz < ZCH; ++zz) {
        union { unsigned u; _Float16 h[2]; } v;
        v.u = p32[((size_t)zz << 18) + base32];          // zz*524288/2
        a0 += (float)v.h[0] * fz[zz];
        a1 += (float)v.h[1] * fz[zz];
    }
    const float inv = 1.f / den;
    float2 o;
    o.x = a0 * inv;
    o.y = a1 * inv;
    *(float2*)&pacc[((size_t)row << 9) + (t << 1)] = o;
    if (t == 0) dmg[row] = mg;
}

// ---------------- K5: proj = pacc @ Wv + bv ----------------
__global__ __launch_bounds__(256) void k_proj(const float* __restrict__ pacc, const float* __restrict__ Wv,
                                              const float* __restrict__ bv, float* __restrict__ proj) {
    const int d0 = blockIdx.x * 64;
    const int r0 = blockIdx.y * 64;
    const int tid = threadIdx.x;
    const int rsub = (tid >> 4) << 2;
    const int dsub = (tid & 15) << 2;
    __shared__ float at[64][68];
    __shared__ float wv[64][68];
    float acc[4][4] = {{0.f, 0.f, 0.f, 0.f}};
    for (int kc = 0; kc < 8; ++kc) {
        const int k0 = kc * 64;
        for (int k = tid; k < 1024; k += 256) {
            const int rr = k >> 4, c4 = (k & 15) << 2;
            *(float4*)&at[rr][c4] = *(const float4*)&pacc[(size_t)(r0 + rr) * DD + k0 + c4];
            *(float4*)&wv[rr][c4] = *(const float4*)&Wv[(size_t)(k0 + rr) * DD + d0 + c4];
        }
        __syncthreads();
        #pragma unroll
        for (int n4 = 0; n4 < 16; ++n4) {
            float4 a4[4];
            #pragma unroll
            for (int i = 0; i < 4; ++i) a4[i] = *(const float4*)&at[rsub + i][n4 << 2];
            const float4 b0 = *(const float4*)&wv[(n4 << 2) + 0][dsub];
            const float4 b1 = *(const float4*)&wv[(n4 << 2) + 1][dsub];
            const float4 b2 = *(const float4*)&wv[(n4 << 2) + 2][dsub];
            const float4 b3 = *(const float4*)&wv[(n4 << 2) + 3][dsub];
            #pragma unroll
            for (int i = 0; i < 4; ++i) {
                const float4 av = a4[i];
                acc[i][0] += av.x * b0.x + av.y * b1.x + av.z * b2.x + av.w * b3.x;
                acc[i][1] += av.x * b0.y + av.y * b1.y + av.z * b2.y + av.w * b3.y;
                acc[i][2] += av.x * b0.z + av.y * b1.z + av.z * b2.z + av.w * b3.z;
                acc[i][3] += av.x * b0.w + av.y * b1.w + av.z * b2.w + av.w * b3.w;
            }
        }
        __syncthreads();
    }
    #pragma unroll
    for (int i = 0; i < 4; ++i) {
        const int d = d0 + dsub;
        float4 v;
        v.x = acc[i][0] + bv[d + 0];
        v.y = acc[i][1] + bv[d + 1];
        v.z = acc[i][2] + bv[d + 2];
        v.w = acc[i][3] + bv[d + 3];
        *(float4*)&proj[(size_t)(r0 + rsub + i) * DD + d] = v;
    }
}

// ---------------- K6: RMSNorm + masks + outputs ----------------
__global__ __launch_bounds__(256) void k_rmsout(const float* __restrict__ proj, const float* __restrict__ norm_w,
                                                const float* __restrict__ dmg, float* __restrict__ out) {
    const int row = blockIdx.x;  // b*64 + l
    const int tid = threadIdx.x;
    __shared__ float red[256];
    const float* pr = proj + (size_t)row * DD;
    const float v0 = pr[tid], v1 = pr[tid + 256];
    red[tid] = v0 * v0 + v1 * v1;
    __syncthreads();
    for (int st = 128; st > 0; st >>= 1) {
        if (tid < st) red[tid] += red[tid + st];
        __syncthreads();
    }
    const float var = red[0] / (float)DD;
    const float r = 1.0f / sqrtf(var + RMS_EPS);
    const int ap = (dmg[row] < -1.0e38f) ? 1 : 0;
    const float msk = ap ? 0.f : 1.f;
    out[(size_t)row * DD + tid]       = v0 * r * norm_w[tid] * msk;
    out[(size_t)row * DD + tid + 256] = v1 * r * norm_w[tid + 256] * msk;
    if (tid == 0) out[(size_t)PSZ + row] = ap ? 1.f : 0.f;
}

extern "C" void kernel_launch(void* const* d_in, const int* in_sizes, int n_in,
                              void* d_out, int out_size, void* d_ws, size_t ws_size,
                              hipStream_t stream) {
    const float* query   = (const float*)d_in[0];
    const float* tokens  = (const float*)d_in[1];
    const int*   pmask   = (const int*)d_in[2];
    const float* latents = (const float*)d_in[3];
    const float* Wq = (const float*)d_in[4];
    const float* bq = (const float*)d_in[5];
    const float* Wk = (const float*)d_in[6];
    const float* bk = (const float*)d_in[7];
    const float* Wv = (const float*)d_in[8];
    const float* bv = (const float*)d_in[9];
    const float* nw = (const float*)d_in[10];

    float* ws = (float*)d_ws;
    float* dmg    = ws;                       // 1024
    float* mzv    = ws + 1024;                // 32768
    float* szv    = ws + 33792;               // 32768
    float* qproj  = ws + 66560;               // 8192
    float* Lk     = ws + 74752;               // 32768
    float* Qk     = ws + 107520;              // 8192
    float* sbL    = ws + 115712;              // 64
    float* sbQ    = ws + 115776;              // 64 (pad to 115968)
    unsigned short* LQbf = (unsigned short*)(ws + 115968);   // 524288 ushorts = 262144 floats
    _Float16* part = (_Float16*)(ws + 115968 + 262144);      // 16777216 halves = 8388608 floats
    float* pacc   = ws + 115968 + 262144 + 8388608;          // 524288
    float* proj   = ws + 115968 + 262144 + 8388608 + 524288; // 524288
    float* out    = (float*)d_out;

    k_qproj<<<dim3(8, 16), 256, 0, stream>>>(query, Wq, bq, qproj);
    k_lkqk<<<dim3(8, 80), 256, 0, stream>>>(latents, qproj, Wk, bk, Lk, Qk, sbL, sbQ);
    k_lqbf<<<dim3(64, 16), 256, 0, stream>>>(Lk, Qk, LQbf);
    k_flash<<<dim3(64, 16), 512, 0, stream>>>(tokens, LQbf, sbL, sbQ, pmask, part, mzv, szv);
    k_combine<<<1024, 256, 0, stream>>>(part, mzv, szv, pacc, dmg);
    k_proj<<<dim3(8, 16), 256, 0, stream>>>(pacc, Wv, bv, proj);
    k_rmsout<<<1024, 256, 0, stream>>>(proj, nw, dmg, out);
}

// Round 13
// 115.578 us; speedup vs baseline: 1.1818x; 1.1818x over previous
//
#include <hip/hip_runtime.h>
#include <hip/hip_bf16.h>
#include <math.h>

#define BB 16
#define NN_ 4096
#define DD 512
#define LL 64
#define SCALE 0.044194173824159216f
#define RMS_EPS 1e-6f
#define MASKVAL -3.0e38f
#define PSZ (BB * LL * DD)   // 524288
#define ZCH 32               // N-chunks (128 tokens each, 2 tiles of 64)

using bf16x8 = __attribute__((ext_vector_type(8))) short;
using f32x4  = __attribute__((ext_vector_type(4))) float;

__device__ __forceinline__ unsigned short f2bf(float x) {
    return __bfloat16_as_ushort(__float2bfloat16(x));
}

__device__ __forceinline__ void gl_lds16(const float* g, char* lds_generic, int lds_byte_off) {
    // wave-uniform LDS base (readfirstlane forces scalarization), per-lane global src
    const int off = __builtin_amdgcn_readfirstlane(lds_byte_off);
    __builtin_amdgcn_global_load_lds(
        (const __attribute__((address_space(1))) unsigned*)(const void*)g,
        (__attribute__((address_space(3))) unsigned*)(void*)(lds_generic + off),
        16, 0, 0);
}

// ---------------- K1: qproj = query @ Wq + bq ----------------
__global__ __launch_bounds__(256) void k_qproj(const float* __restrict__ query, const float* __restrict__ Wq,
                                               const float* __restrict__ bq, float* __restrict__ qproj) {
    const int b = blockIdx.y;
    const int dl = threadIdx.x & 63;
    const int d = (blockIdx.x << 6) + dl;
    const int wv = threadIdx.x >> 6;
    __shared__ float q[DD];
    __shared__ float red[4][64];
    for (int e = threadIdx.x; e < DD; e += 256) q[e] = query[b * DD + e];
    __syncthreads();
    float acc = 0.f;
    #pragma unroll 8
    for (int i = 0; i < 128; ++i) {
        const int e = (wv << 7) + i;
        acc += q[e] * Wq[(size_t)e * DD + d];
    }
    red[wv][dl] = acc;
    __syncthreads();
    if (threadIdx.x < 64) {
        const int dd = (blockIdx.x << 6) + threadIdx.x;
        qproj[(size_t)b * DD + dd] = red[0][threadIdx.x] + red[1][threadIdx.x] +
                                     red[2][threadIdx.x] + red[3][threadIdx.x] + bq[dd];
    }
}

// ---------------- K2: Lk/Qk = rows @ Wk^T, sbL/sbQ = rows . bk ----------------
__global__ __launch_bounds__(256) void k_lkqk(const float* __restrict__ latents, const float* __restrict__ qproj,
                                              const float* __restrict__ Wk, const float* __restrict__ bk,
                                              float* __restrict__ Lk, float* __restrict__ Qk,
                                              float* __restrict__ sbL, float* __restrict__ sbQ) {
    const int r = blockIdx.y;
    const int e0 = blockIdx.x << 6;
    const int tid = threadIdx.x;
    __shared__ float row[DD];
    const float* src = (r < LL) ? (latents + (size_t)r * DD) : (qproj + (size_t)(r - LL) * DD);
    for (int dd = tid; dd < DD; dd += 256) row[dd] = src[dd];
    __syncthreads();
    const int e = e0 + (tid >> 2);
    const int part = tid & 3;
    const float4* w4 = (const float4*)(Wk + (size_t)e * DD);
    const float4* r4 = (const float4*)row;
    float acc = 0.f;
    #pragma unroll 8
    for (int j = 0; j < 32; ++j) {
        const int d4 = part + (j << 2);
        const float4 w = w4[d4], rr = r4[d4];
        acc += w.x * rr.x + w.y * rr.y + w.z * rr.z + w.w * rr.w;
    }
    acc += __shfl_xor(acc, 1);
    acc += __shfl_xor(acc, 2);
    if (part == 0) {
        if (r < LL) Lk[(size_t)r * DD + e] = acc;
        else        Qk[(size_t)(r - LL) * DD + e] = acc;
    }
    if (blockIdx.x == 0 && tid < 64) {
        float p = 0.f;
        #pragma unroll
        for (int dd = tid; dd < DD; dd += 64) p += bk[dd] * row[dd];
        #pragma unroll
        for (int off = 32; off > 0; off >>= 1) p += __shfl_xor(p, off);
        if (tid == 0) { if (r < LL) sbL[r] = p; else sbQ[r - LL] = p; }
    }
}

// ---------------- K2b: LQbf[b][l][d] = bf16(Lk[l][d] + Qk[b][d]) ----------------
__global__ __launch_bounds__(256) void k_lqbf(const float* __restrict__ Lk, const float* __restrict__ Qk,
                                              unsigned short* __restrict__ LQbf) {
    const int l = blockIdx.x, b = blockIdx.y;
    const int d = threadIdx.x << 1;
    const float2 lv = *(const float2*)&Lk[(size_t)l * DD + d];
    const float2 qv = *(const float2*)&Qk[(size_t)b * DD + d];
    const unsigned o = (unsigned)f2bf(lv.x + qv.x) | ((unsigned)f2bf(lv.y + qv.y) << 16);
    *(unsigned*)&LQbf[(size_t)((b << 6) + l) * DD + d] = o;
}

// ---------------- K3: fused flash (v10: global_load_lds async staging, counted vmcnt + raw barriers) ----------------
// grid (z=32, b=16) = 512 blocks, 512 threads (8 waves), 2 blocks/CU (LDS ~64KB).
__global__ __launch_bounds__(512, 2) void k_flash(const float* __restrict__ tokens,
                                                  const unsigned short* __restrict__ LQbf,
                                                  const float* __restrict__ sbL, const float* __restrict__ sbQ,
                                                  const int* __restrict__ pmask,
                                                  _Float16* __restrict__ part,
                                                  float* __restrict__ mz, float* __restrict__ sz) {
    const int z = blockIdx.x, b = blockIdx.y;
    const int tid = threadIdx.x;
    const int lane = tid & 63, w = tid >> 6;
    const int r16 = lane & 15, kl = lane >> 4;

    __shared__ float sB[2][64][64];       // f32 token slice [n][d-blk swizzled], LINEAR (gload_lds), dbuf: 32K
    __shared__ unsigned short sP[64][72]; // P bf16 [l][n(64)], 144B rows (16B-aligned): 9.2K
    __shared__ int sTw[8][32][20];        // per-wave PV window [e(32)][pair16+pad]: 20.5K
    __shared__ float s_mn[64], s_sum[64], s_rr[64];
    __shared__ float s_pmax[2][64], s_psum[2][64];

    const int lq = (w & 3) << 4;        // QK^T wave l-block (16)
    const int nq = (w >> 2) << 5;       // QK^T wave n-block (32)

    // ---- register-resident A-fragments (bf16, from LQbf; 64 VGPR) ----
    bf16x8 afLQ[16];
    {
        const unsigned short* lqrow = &LQbf[(size_t)((b << 6) + lq + r16) * DD];
        #pragma unroll
        for (int f = 0; f < 16; ++f)
            afLQ[f] = *(const bf16x8*)&lqrow[(f << 5) + (kl << 3)];
    }

    f32x4 acc[4][4];                    // PV: 64 l x 64 e per wave
    #pragma unroll
    for (int m = 0; m < 4; ++m)
        #pragma unroll
        for (int ef = 0; ef < 4; ++ef)
            acc[m][ef] = (f32x4){0.f, 0.f, 0.f, 0.f};

    if (tid < 64) { s_mn[tid] = MASKVAL; s_sum[tid] = 0.f; }

    const float sq = sbQ[b];
    float sbl[4];
    #pragma unroll
    for (int q = 0; q < 4; ++q) sbl[q] = sbL[lq + (kl << 2) + q];

    // gload geometry: wave w stages rows 8w..8w+7; lane -> (row = +lane>>4, dblk = lane&15)
    const int rA = (w << 3) + (lane >> 4);
    const int rB = rA + 4;
    const int dbA = ((lane & 15) ^ (rA & 15)) << 2;   // source-swizzled f32 col
    const int dbB = ((lane & 15) ^ (rB & 15)) << 2;
    const int e0w = w << 6;               // PV wave e-slice base (64)
    char* sB_base = (char*)&sB[0][0][0];
    __syncthreads();

    for (int t = 0; t < 2; ++t) {
        const int n0 = (z << 7) + (t << 6);
        f32x4 accS[2];
        accS[0] = (f32x4){0.f, 0.f, 0.f, 0.f};
        accS[1] = (f32x4){0.f, 0.f, 0.f, 0.f};

        const size_t gb = (size_t)((b << 12) + n0);

        // prologue: issue slice 0 into buf 0
        gl_lds16(&tokens[(gb + rA) * DD + dbA], sB_base, ((w << 3) << 8));
        gl_lds16(&tokens[(gb + rB) * DD + dbB], sB_base, (((w << 3) + 4) << 8));

        // ---- phase 1: QK^T over 8 d-slices, counted vmcnt + raw barriers ----
        #pragma unroll
        for (int s8 = 0; s8 < 8; ++s8) {
            const int cur = s8 & 1;
            asm volatile("s_waitcnt vmcnt(0)" ::: "memory");   // own DMA for slice s8 landed
            __builtin_amdgcn_s_barrier();                      // raw: no drain of others' queues
            if (s8 < 7) {
                const int nxt = (s8 + 1) & 1;
                gl_lds16(&tokens[(gb + rA) * DD + ((s8 + 1) << 6) + dbA], sB_base,
                         (nxt << 14) + ((w << 3) << 8));
                gl_lds16(&tokens[(gb + rB) * DD + ((s8 + 1) << 6) + dbB], sB_base,
                         (nxt << 14) + (((w << 3) + 4) << 8));
            }
            #pragma unroll
            for (int kk2 = 0; kk2 < 2; ++kk2) {
                const bf16x8 af = afLQ[(s8 << 1) | kk2];
                #pragma unroll
                for (int nf = 0; nf < 2; ++nf) {
                    const int n = nq + (nf << 4) + r16;
                    const int lb = (kk2 << 3) + (kl << 1);
                    const float4 f0 = *(const float4*)&sB[cur][n][(lb ^ r16) << 2];
                    const float4 f1 = *(const float4*)&sB[cur][n][((lb + 1) ^ r16) << 2];
                    bf16x8 bfr;
                    bfr[0] = (short)f2bf(f0.x); bfr[1] = (short)f2bf(f0.y);
                    bfr[2] = (short)f2bf(f0.z); bfr[3] = (short)f2bf(f0.w);
                    bfr[4] = (short)f2bf(f1.x); bfr[5] = (short)f2bf(f1.y);
                    bfr[6] = (short)f2bf(f1.z); bfr[7] = (short)f2bf(f1.w);
                    accS[nf] = __builtin_amdgcn_mfma_f32_16x16x32_bf16(af, bfr, accS[nf], 0, 0, 0);
                }
            }
        }

        // ---- epilogue: bias+scale+mask, in-register stats (proven v8 path) ----
        float sv[2][4], tm4[4];
        #pragma unroll
        for (int nf = 0; nf < 2; ++nf) {
            const int ncol = nq + (nf << 4) + r16;
            const int pm = pmask[(size_t)(b << 12) + n0 + ncol];
            #pragma unroll
            for (int q = 0; q < 4; ++q) {
                const float sval = (accS[nf][q] + sbl[q] + sq) * SCALE;
                sv[nf][q] = pm ? MASKVAL : sval;
            }
        }
        #pragma unroll
        for (int q = 0; q < 4; ++q) tm4[q] = fmaxf(sv[0][q], sv[1][q]);
        #pragma unroll
        for (int off = 1; off <= 8; off <<= 1)
            #pragma unroll
            for (int q = 0; q < 4; ++q) tm4[q] = fmaxf(tm4[q], __shfl_xor(tm4[q], off));
        if (r16 == 0) {
            #pragma unroll
            for (int q = 0; q < 4; ++q) s_pmax[w >> 2][lq + (kl << 2) + q] = tm4[q];
        }
        __syncthreads();
        if (tid < 64) {
            const float tmx = fmaxf(s_pmax[0][tid], s_pmax[1][tid]);
            const float mo = s_mn[tid];
            const float mn = fmaxf(mo, tmx);
            s_rr[tid] = __expf(mo - mn);
            s_mn[tid] = mn;
        }
        __syncthreads();
        float ps4[4];
        #pragma unroll
        for (int q = 0; q < 4; ++q) {
            const int l = lq + (kl << 2) + q;
            const float mn = s_mn[l];
            const float p0 = __expf(sv[0][q] - mn);
            const float p1 = __expf(sv[1][q] - mn);
            sP[l][nq + r16] = f2bf(p0);
            sP[l][nq + 16 + r16] = f2bf(p1);
            ps4[q] = p0 + p1;
        }
        #pragma unroll
        for (int off = 1; off <= 8; off <<= 1)
            #pragma unroll
            for (int q = 0; q < 4; ++q) ps4[q] += __shfl_xor(ps4[q], off);
        if (r16 == 0) {
            #pragma unroll
            for (int q = 0; q < 4; ++q) s_psum[w >> 2][lq + (kl << 2) + q] = ps4[q];
        }
        #pragma unroll
        for (int m = 0; m < 4; ++m) {
            #pragma unroll
            for (int q = 0; q < 4; ++q) {
                const float rrr = s_rr[(m << 4) + (kl << 2) + q];
                #pragma unroll
                for (int ef = 0; ef < 4; ++ef) acc[m][ef][q] *= rrr;
            }
        }
        __syncthreads();
        if (tid < 64) s_sum[tid] = s_sum[tid] * s_rr[tid] + s_psum[0][tid] + s_psum[1][tid];

        // ---- phase 2: PV, per-wave 64-e slice in two 32-e windows (no cross-wave barriers) ----
        #pragma unroll
        for (int kk = 0; kk < 2; ++kk) {
            bf16x8 pa[4];
            #pragma unroll
            for (int m = 0; m < 4; ++m)
                pa[m] = *(const bf16x8*)&sP[(m << 4) + r16][(kk << 5) + (kl << 3)];
            #pragma unroll
            for (int h = 0; h < 2; ++h) {
                #pragma unroll
                for (int rep = 0; rep < 2; ++rep) {
                    const int p = (lane >> 3) + (rep << 3);       // pair 0..15
                    const int e4 = (lane & 7) << 2;               // e offset 0..28
                    const float* tp = &tokens[(size_t)((b << 12) + n0 + (kk << 5) + (p << 1)) * DD
                                              + e0w + (h << 5) + e4];
                    const float4 t0 = *(const float4*)tp;
                    const float4 t1 = *(const float4*)(tp + DD);
                    const float* a0 = (const float*)&t0;
                    const float* a1 = (const float*)&t1;
                    #pragma unroll
                    for (int j = 0; j < 4; ++j) {
                        const int e = e4 + j;
                        const int col = p ^ ((((e >> 2) ^ (e >> 4)) & 3) << 2);
                        sTw[w][e][col] = (int)((unsigned)f2bf(a0[j]) | ((unsigned)f2bf(a1[j]) << 16));
                    }
                }
                #pragma unroll
                for (int ef2 = 0; ef2 < 2; ++ef2) {
                    const int e = (ef2 << 4) + r16;
                    const int col4 = (kl << 2) ^ ((((e >> 2) ^ (e >> 4)) & 3) << 2);
                    const bf16x8 bv = *(const bf16x8*)&sTw[w][e][col4];
                    const int ef = (h << 1) + ef2;
                    #pragma unroll
                    for (int m = 0; m < 4; ++m)
                        acc[m][ef] = __builtin_amdgcn_mfma_f32_16x16x32_bf16(pa[m], bv, acc[m][ef], 0, 0, 0);
                }
            }
        }
        __syncthreads();
    }

    // ---- write partials (f16) ----
    #pragma unroll
    for (int m = 0; m < 4; ++m) {
        #pragma unroll
        for (int ef = 0; ef < 4; ++ef) {
            #pragma unroll
            for (int q = 0; q < 4; ++q) {
                const int l = (m << 4) + (kl << 2) + q;
                const int e = e0w + (ef << 4) + r16;
                part[(size_t)((z << 10) + (b << 6) + l) * DD + e] = (_Float16)acc[m][ef][q];
            }
        }
    }
    if (tid < 64) {
        mz[(z << 10) + (b << 6) + tid] = s_mn[tid];
        sz[(z << 10) + (b << 6) + tid] = s_sum[tid];
    }
}

// ---------------- K4: combine chunks with rescale + divide (vectorized loads) ----------------
__global__ __launch_bounds__(256) void k_combine(const _Float16* __restrict__ part,
                                                 const float* __restrict__ mz, const float* __restrict__ sz,
                                                 float* __restrict__ pacc, float* __restrict__ dmg) {
    const int row = blockIdx.x;   // b*64 + l
    const int t = threadIdx.x;
    float mg = MASKVAL;
    float mv[ZCH];
    #pragma unroll
    for (int zz = 0; zz < ZCH; ++zz) {
        mv[zz] = mz[(zz << 10) + row];
        mg = fmaxf(mg, mv[zz]);
    }
    float den = 0.f;
    float fz[ZCH];
    #pragma unroll
    for (int zz = 0; zz < ZCH; ++zz) {
        fz[zz] = __expf(mv[zz] - mg);
        den += sz[(zz << 10) + row] * fz[zz];
    }
    const unsigned* p32 = (const unsigned*)part;
    const unsigned base32 = (unsigned)(row << 8) + t;
    float a0 = 0.f, a1 = 0.f;
    #pragma unroll 8
    for (int zz = 0; zz < ZCH; ++zz) {
        union { unsigned u; _Float16 h[2]; } v;
        v.u = p32[((size_t)zz << 18) + base32];
        a0 += (float)v.h[0] * fz[zz];
        a1 += (float)v.h[1] * fz[zz];
    }
    const float inv = 1.f / den;
    float2 o;
    o.x = a0 * inv;
    o.y = a1 * inv;
    *(float2*)&pacc[((size_t)row << 9) + (t << 1)] = o;
    if (t == 0) dmg[row] = mg;
}

// ---------------- K5: proj = pacc @ Wv + bv ----------------
__global__ __launch_bounds__(256) void k_proj(const float* __restrict__ pacc, const float* __restrict__ Wv,
                                              const float* __restrict__ bv, float* __restrict__ proj) {
    const int d0 = blockIdx.x * 64;
    const int r0 = blockIdx.y * 64;
    const int tid = threadIdx.x;
    const int rsub = (tid >> 4) << 2;
    const int dsub = (tid & 15) << 2;
    __shared__ float at[64][68];
    __shared__ float wv[64][68];
    float acc[4][4] = {{0.f, 0.f, 0.f, 0.f}};
    for (int kc = 0; kc < 8; ++kc) {
        const int k0 = kc * 64;
        for (int k = tid; k < 1024; k += 256) {
            const int rr = k >> 4, c4 = (k & 15) << 2;
            *(float4*)&at[rr][c4] = *(const float4*)&pacc[(size_t)(r0 + rr) * DD + k0 + c4];
            *(float4*)&wv[rr][c4] = *(const float4*)&Wv[(size_t)(k0 + rr) * DD + d0 + c4];
        }
        __syncthreads();
        #pragma unroll
        for (int n4 = 0; n4 < 16; ++n4) {
            float4 a4[4];
            #pragma unroll
            for (int i = 0; i < 4; ++i) a4[i] = *(const float4*)&at[rsub + i][n4 << 2];
            const float4 b0 = *(const float4*)&wv[(n4 << 2) + 0][dsub];
            const float4 b1 = *(const float4*)&wv[(n4 << 2) + 1][dsub];
            const float4 b2 = *(const float4*)&wv[(n4 << 2) + 2][dsub];
            const float4 b3 = *(const float4*)&wv[(n4 << 2) + 3][dsub];
            #pragma unroll
            for (int i = 0; i < 4; ++i) {
                const float4 av = a4[i];
                acc[i][0] += av.x * b0.x + av.y * b1.x + av.z * b2.x + av.w * b3.x;
                acc[i][1] += av.x * b0.y + av.y * b1.y + av.z * b2.y + av.w * b3.y;
                acc[i][2] += av.x * b0.z + av.y * b1.z + av.z * b2.z + av.w * b3.z;
                acc[i][3] += av.x * b0.w + av.y * b1.w + av.z * b2.w + av.w * b3.w;
            }
        }
        __syncthreads();
    }
    #pragma unroll
    for (int i = 0; i < 4; ++i) {
        const int d = d0 + dsub;
        float4 v;
        v.x = acc[i][0] + bv[d + 0];
        v.y = acc[i][1] + bv[d + 1];
        v.z = acc[i][2] + bv[d + 2];
        v.w = acc[i][3] + bv[d + 3];
        *(float4*)&proj[(size_t)(r0 + rsub + i) * DD + d] = v;
    }
}

// ---------------- K6: RMSNorm + masks + outputs ----------------
__global__ __launch_bounds__(256) void k_rmsout(const float* __restrict__ proj, const float* __restrict__ norm_w,
                                                const float* __restrict__ dmg, float* __restrict__ out) {
    const int row = blockIdx.x;  // b*64 + l
    const int tid = threadIdx.x;
    __shared__ float red[256];
    const float* pr = proj + (size_t)row * DD;
    const float v0 = pr[tid], v1 = pr[tid + 256];
    red[tid] = v0 * v0 + v1 * v1;
    __syncthreads();
    for (int st = 128; st > 0; st >>= 1) {
        if (tid < st) red[tid] += red[tid + st];
        __syncthreads();
    }
    const float var = red[0] / (float)DD;
    const float r = 1.0f / sqrtf(var + RMS_EPS);
    const int ap = (dmg[row] < -1.0e38f) ? 1 : 0;
    const float msk = ap ? 0.f : 1.f;
    out[(size_t)row * DD + tid]       = v0 * r * norm_w[tid] * msk;
    out[(size_t)row * DD + tid + 256] = v1 * r * norm_w[tid + 256] * msk;
    if (tid == 0) out[(size_t)PSZ + row] = ap ? 1.f : 0.f;
}

extern "C" void kernel_launch(void* const* d_in, const int* in_sizes, int n_in,
                              void* d_out, int out_size, void* d_ws, size_t ws_size,
                              hipStream_t stream) {
    const float* query   = (const float*)d_in[0];
    const float* tokens  = (const float*)d_in[1];
    const int*   pmask   = (const int*)d_in[2];
    const float* latents = (const float*)d_in[3];
    const float* Wq = (const float*)d_in[4];
    const float* bq = (const float*)d_in[5];
    const float* Wk = (const float*)d_in[6];
    const float* bk = (const float*)d_in[7];
    const float* Wv = (const float*)d_in[8];
    const float* bv = (const float*)d_in[9];
    const float* nw = (const float*)d_in[10];

    float* ws = (float*)d_ws;
    float* dmg    = ws;                       // 1024
    float* mzv    = ws + 1024;                // 32768
    float* szv    = ws + 33792;               // 32768
    float* qproj  = ws + 66560;               // 8192
    float* Lk     = ws + 74752;               // 32768
    float* Qk     = ws + 107520;              // 8192
    float* sbL    = ws + 115712;              // 64
    float* sbQ    = ws + 115776;              // 64 (pad to 115968)
    unsigned short* LQbf = (unsigned short*)(ws + 115968);   // 524288 ushorts = 262144 floats
    _Float16* part = (_Float16*)(ws + 115968 + 262144);      // 16777216 halves = 8388608 floats
    float* pacc   = ws + 115968 + 262144 + 8388608;          // 524288
    float* proj   = ws + 115968 + 262144 + 8388608 + 524288; // 524288
    float* out    = (float*)d_out;

    k_qproj<<<dim3(8, 16), 256, 0, stream>>>(query, Wq, bq, qproj);
    k_lkqk<<<dim3(8, 80), 256, 0, stream>>>(latents, qproj, Wk, bk, Lk, Qk, sbL, sbQ);
    k_lqbf<<<dim3(64, 16), 256, 0, stream>>>(Lk, Qk, LQbf);
    k_flash<<<dim3(ZCH, 16), 512, 0, stream>>>(tokens, LQbf, sbL, sbQ, pmask, part, mzv, szv);
    k_combine<<<1024, 256, 0, stream>>>(part, mzv, szv, pacc, dmg);
    k_proj<<<dim3(8, 16), 256, 0, stream>>>(pacc, Wv, bv, proj);
    k_rmsout<<<1024, 256, 0, stream>>>(proj, nw, dmg, out);
}